// Round 1
// 537.639 us; speedup vs baseline: 1.0557x; 1.0557x over previous
//
#include <hip/hip_runtime.h>
#include <stdint.h>

// CoedgeConvLayer: out = relu(f@Ws + f[ni]@Wn + f[pi]@Wp + f[mi]@Wm + sum_b)
// One gathered GEMM  M=200000, K=1024 (4 phases x 256), N=256 in bf16 MFMA.
// ws layout: [feat_bf16 102.4MB][Bpack 512KB][bias 1KB]
// R1: phase-pipelined double-buffered gathers (counted-vmcnt safe ordering:
//     stage(p+1) issued AFTER last B-load of phase p), raw s_barrier (1/phase),
//     dense-load k_conv.

#define D 256
#define BM 64

typedef __bf16 bf16x8 __attribute__((ext_vector_type(8)));
typedef float f32x4 __attribute__((ext_vector_type(4)));

static __device__ __forceinline__ uint16_t f32_to_bf16_rne(uint32_t u) {
    return (uint16_t)((u + 0x7FFFu + ((u >> 16) & 1u)) >> 16);
}

// ---------- prep: features f32 -> bf16, fully dense loads/stores ----------
// block covers 2048 floats: two dense float4 passes of 1024 floats each.
__global__ void k_conv(const float* __restrict__ f, uint16_t* __restrict__ o, long total) {
    long base = (long)blockIdx.x * 2048;
    int t = threadIdx.x;
#pragma unroll
    for (int pass = 0; pass < 2; pass++) {
        long i = base + pass * 1024 + (long)t * 4;
        if (i + 4 > total) return;
        uint32_t v[4];
        *(uint4*)v = *(const uint4*)(f + i);
        union { uint16_t u16[4]; uint2 v2; } r;
#pragma unroll
        for (int j = 0; j < 4; j++) r.u16[j] = f32_to_bf16_rne(v[j]);
        *(uint2*)(o + i) = r.v2;
    }
}

// ---------- prep: pack W_cat [1024,256] f32 into MFMA B-fragment layout, bf16 ----------
// Bpack[((ksg*16 + nt)*64 + lane)*8 + j] = bf16( W_{ksg>>3}[ (ksg&7)*32 + (lane>>4)*8 + j ][ nt*16 + (lane&15) ] )
__global__ void k_pack(const float* __restrict__ Ws, const float* __restrict__ Wn,
                       const float* __restrict__ Wp, const float* __restrict__ Wm,
                       uint16_t* __restrict__ Bp) {
    int b = blockIdx.x;      // 0..511 = ksg*16 + nt
    int l = threadIdx.x;     // 0..63
    int ksg = b >> 4, nt = b & 15;
    int ph = ksg >> 3;
    const float* W = (ph == 0) ? Ws : (ph == 1) ? Wn : (ph == 2) ? Wp : Wm;
    int kl = (ksg & 7) * 32 + (l >> 4) * 8;
    int n  = nt * 16 + (l & 15);
    uint16_t* dst = Bp + ((size_t)b * 64 + l) * 8;
#pragma unroll
    for (int j = 0; j < 8; j++) {
        uint32_t u = __builtin_bit_cast(uint32_t, W[(size_t)(kl + j) * D + n]);
        dst[j] = f32_to_bf16_rne(u);
    }
}

__global__ void k_bias(const float* __restrict__ b0, const float* __restrict__ b1,
                       const float* __restrict__ b2, const float* __restrict__ b3,
                       float* __restrict__ btot) {
    int t = threadIdx.x;
    if (t < D) btot[t] = b0[t] + b1[t] + b2[t] + b3[t];
}

// ---------- main gathered GEMM ----------
// block: 64 rows x 256 cols, 256 threads (4 waves, wave w owns cols [w*64, w*64+64))
// K-loop: 4 phases (self/next/prev/mate), each K=256.
// Double-buffered LDS A-tile; phase p+1's 8 global_load_lds per wave are issued
// AFTER the last B-fragment load of phase p (ks6/7 B preloaded to regs), so no
// compiler vmcnt wait inside the remaining compute drains them (in-order retire).
// One raw s_barrier per phase; vmcnt(0)+barrier at phase top makes staging visible.
typedef __attribute__((address_space(1))) uint32_t gu32;
typedef __attribute__((address_space(3))) uint32_t lu32;

__global__ __launch_bounds__(256, 2) void k_gemm(
    const uint16_t* __restrict__ fb,
    const int* __restrict__ ni, const int* __restrict__ pi, const int* __restrict__ mi,
    const uint16_t* __restrict__ Bp, const float* __restrict__ btot,
    float* __restrict__ out, int nrows)
{
    __shared__ uint16_t As[2][BM * D];       // 2 x 32 KB, row-major [64][256] (swizzled)
    const int t  = threadIdx.x;
    const int w  = t >> 6;
    const int l  = t & 63;
    const int ml = l & 15;
    const int q  = l >> 4;
    const int m0 = blockIdx.x * BM;

    f32x4 acc[4][4] = {};                    // [m-tile][n-tile]

    const int rpar = w * 16 + (l >> 5);      // staging: lanes 0-31 row+0, 32-63 row+1
    const int cs   = l & 31;                 // staging 16B-chunk index within row

    // Precompute per-lane gather byte-offsets for all 4 phases (indices loaded once).
    uint32_t off0[8], off1[8], off2[8], off3[8];
#pragma unroll
    for (int e = 0; e < 8; e++) {
        int r = rpar + e * 2;
        int rowg = m0 + r; if (rowg >= nrows) rowg = nrows - 1;
        uint32_t co = (uint32_t)((cs ^ (r & 7)) * 16);   // fetch-side swizzle, bytes
        off0[e] = (uint32_t)rowg * (D * 2) + co;
        off1[e] = (uint32_t)ni[rowg] * (D * 2) + co;
        off2[e] = (uint32_t)pi[rowg] * (D * 2) + co;
        off3[e] = (uint32_t)mi[rowg] * (D * 2) + co;
    }

#define STAGE(OFFA, BUF) do { \
        uint16_t* _s = &As[BUF][(w * 16) * D]; \
        _Pragma("unroll") \
        for (int e = 0; e < 8; e++) { \
            const char* _g = (const char*)fb + (OFFA)[e]; \
            __builtin_amdgcn_global_load_lds((const gu32*)_g, (lu32*)(_s + e * 2 * D), 16, 0, 0); \
        } \
    } while (0)

#define KSTEP(BUF, BB, KS) do { \
        bf16x8 bfr[4]; \
        _Pragma("unroll") \
        for (int j = 0; j < 4; j++) bfr[j] = *(const bf16x8*)((BB) + ((KS) * 16 + j) * 512); \
        bf16x8 afr[4]; \
        _Pragma("unroll") \
        for (int mt = 0; mt < 4; mt++) { \
            int r = mt * 16 + ml; \
            int ch = ((KS) * 4 + q) ^ (r & 7); \
            afr[mt] = *(const bf16x8*)&As[BUF][r * D + ch * 8]; \
        } \
        _Pragma("unroll") \
        for (int mt = 0; mt < 4; mt++) \
            _Pragma("unroll") \
            for (int j = 0; j < 4; j++) \
                acc[mt][j] = __builtin_amdgcn_mfma_f32_16x16x32_bf16(afr[mt], bfr[j], acc[mt][j], 0, 0, 0); \
    } while (0)

#define KSTEP_PRE(BUF, BPRE, KS) do { \
        bf16x8 afr[4]; \
        _Pragma("unroll") \
        for (int mt = 0; mt < 4; mt++) { \
            int r = mt * 16 + ml; \
            int ch = ((KS) * 4 + q) ^ (r & 7); \
            afr[mt] = *(const bf16x8*)&As[BUF][r * D + ch * 8]; \
        } \
        _Pragma("unroll") \
        for (int mt = 0; mt < 4; mt++) \
            _Pragma("unroll") \
            for (int j = 0; j < 4; j++) \
                acc[mt][j] = __builtin_amdgcn_mfma_f32_16x16x32_bf16(afr[mt], (BPRE)[j], acc[mt][j], 0, 0, 0); \
    } while (0)

#define WAITBAR() do { \
        asm volatile("s_waitcnt vmcnt(0)" ::: "memory"); \
        __builtin_amdgcn_s_barrier(); \
        __builtin_amdgcn_sched_barrier(0); \
    } while (0)

    // PHASE: top wait+barrier makes stage(P) visible; ks0..5 stream B from L2;
    // ks6/7's B preloaded to regs; THEN stage(P+1) issued (newest vmem) so the
    // remaining MFMAs' waits (vmcnt(8)) never drain it; it flies across the
    // next phase-top barrier.
#define PHASE(P, BUF, OFFNEXT, LAST) do { \
        WAITBAR(); \
        const uint16_t* bb = Bp + (((size_t)(P) * 128 + w * 4) * 64 + l) * 8; \
        KSTEP(BUF, bb, 0); KSTEP(BUF, bb, 1); KSTEP(BUF, bb, 2); \
        KSTEP(BUF, bb, 3); KSTEP(BUF, bb, 4); KSTEP(BUF, bb, 5); \
        bf16x8 b6[4], b7[4]; \
        _Pragma("unroll") \
        for (int j = 0; j < 4; j++) { \
            b6[j] = *(const bf16x8*)(bb + (6 * 16 + j) * 512); \
            b7[j] = *(const bf16x8*)(bb + (7 * 16 + j) * 512); \
        } \
        if (!(LAST)) { \
            __builtin_amdgcn_sched_barrier(0); \
            STAGE(OFFNEXT, (BUF) ^ 1); \
            __builtin_amdgcn_sched_barrier(0); \
        } \
        KSTEP_PRE(BUF, b6, 6); \
        KSTEP_PRE(BUF, b7, 7); \
    } while (0)

    STAGE(off0, 0);
    PHASE(0, 0, off1, 0);
    PHASE(1, 1, off2, 0);
    PHASE(2, 0, off3, 0);
    PHASE(3, 1, off0, 1);

#undef PHASE
#undef WAITBAR
#undef KSTEP_PRE
#undef KSTEP
#undef STAGE

    // epilogue: C/D layout col=lane&15, row=(lane>>4)*4+reg  [m89-verified]
#pragma unroll
    for (int j = 0; j < 4; j++) {
        int n = (w * 4 + j) * 16 + ml;
        float bv = btot[n];
#pragma unroll
        for (int mt = 0; mt < 4; mt++) {
#pragma unroll
            for (int rg = 0; rg < 4; rg++) {
                int row = m0 + mt * 16 + q * 4 + rg;
                if (row < nrows) {
                    float v = acc[mt][j][rg] + bv;
                    out[(size_t)row * D + n] = v > 0.f ? v : 0.f;
                }
            }
        }
    }
}

// ---------- fallback (ws too small): naive fp32, correct but slow ----------
__global__ void k_naive(const float* __restrict__ f,
                        const int* __restrict__ ni, const int* __restrict__ pi,
                        const int* __restrict__ mi,
                        const float* __restrict__ Ws, const float* __restrict__ bs,
                        const float* __restrict__ Wn, const float* __restrict__ bn,
                        const float* __restrict__ Wp, const float* __restrict__ bp,
                        const float* __restrict__ Wm, const float* __restrict__ bm,
                        float* __restrict__ out) {
    int row = blockIdx.x, n = threadIdx.x;
    const float* f0 = f + (size_t)row * D;
    const float* f1 = f + (size_t)ni[row] * D;
    const float* f2 = f + (size_t)pi[row] * D;
    const float* f3 = f + (size_t)mi[row] * D;
    float s = bs[n] + bn[n] + bp[n] + bm[n];
    for (int k = 0; k < D; k++)
        s += f0[k] * Ws[k * D + n] + f1[k] * Wn[k * D + n] +
             f2[k] * Wp[k * D + n] + f3[k] * Wm[k * D + n];
    out[(size_t)row * D + n] = s > 0.f ? s : 0.f;
}

extern "C" void kernel_launch(void* const* d_in, const int* in_sizes, int n_in,
                              void* d_out, int out_size, void* d_ws, size_t ws_size,
                              hipStream_t stream) {
    const float* feat = (const float*)d_in[0];
    const int*   ni   = (const int*)d_in[1];
    const int*   pi   = (const int*)d_in[2];
    const int*   mi   = (const int*)d_in[3];
    const float* Ws   = (const float*)d_in[4];
    const float* bs   = (const float*)d_in[5];
    const float* Wn   = (const float*)d_in[6];
    const float* bn   = (const float*)d_in[7];
    const float* Wp   = (const float*)d_in[8];
    const float* bp   = (const float*)d_in[9];
    const float* Wm   = (const float*)d_in[10];
    const float* bm   = (const float*)d_in[11];
    float* out = (float*)d_out;

    int nrows = in_sizes[1];
    size_t feat_elems = (size_t)nrows * D;
    size_t fb_bytes   = feat_elems * 2;
    size_t bp_off     = fb_bytes;                 // 16B aligned (nrows*512)
    size_t bias_off   = bp_off + (size_t)1024 * D * 2;
    size_t need       = bias_off + (size_t)D * 4;

    if (ws_size < need) {
        k_naive<<<nrows, D, 0, stream>>>(feat, ni, pi, mi, Ws, bs, Wn, bn, Wp, bp, Wm, bm, out);
        return;
    }

    uint16_t* fbuf = (uint16_t*)d_ws;
    uint16_t* Bpk  = (uint16_t*)((char*)d_ws + bp_off);
    float*    btot = (float*)((char*)d_ws + bias_off);

    long total = (long)feat_elems;
    int cblocks = (int)((total + 2047) / 2048);
    k_conv<<<cblocks, 256, 0, stream>>>(feat, fbuf, total);
    k_pack<<<512, 64, 0, stream>>>(Ws, Wn, Wp, Wm, Bpk);
    k_bias<<<1, 256, 0, stream>>>(bs, bn, bp, bm, btot);
    k_gemm<<<(nrows + BM - 1) / BM, 256, 0, stream>>>(fbuf, ni, pi, mi, Bpk, btot, out, nrows);
}